// Round 1
// baseline (651.456 us; speedup 1.0000x reference)
//
#include <hip/hip_runtime.h>
#include <math.h>

// Problem constants (fixed by the reference)
#define N_NODES 50000
#define N_EDGES 800000
#define FN_DIM 16
#define HD 64
#define NL 3
#define ELIST_CAP 262144   // worst-case compacted edge list (expected ~5k)

// ---------- wave-64 helpers ----------
__device__ __forceinline__ float wsum64(float v) {
    #pragma unroll
    for (int o = 1; o < 64; o <<= 1) v += __shfl_xor(v, o);
    return v;
}
__device__ __forceinline__ float wmax64(float v) {
    #pragma unroll
    for (int o = 1; o < 64; o <<= 1) v = fmaxf(v, __shfl_xor(v, o));
    return v;
}
__device__ __forceinline__ float lrelu02(float v) { return v > 0.f ? v : 0.2f * v; }

// ---------- receptive-field discovery ----------
__global__ void k_init(int* need0, int* need1, int* need2, int* cnt) {
    int i = blockIdx.x * blockDim.x + threadIdx.x;
    if (i < N_NODES) {
        int v = (i == 0) ? 1 : 0;
        need0[i] = v; need1[i] = v; need2[i] = v;
    }
    if (i < 32) cnt[i] = 0;
}

__global__ void k_mark2(const int* __restrict__ ei, int* need0, int* need1, int* need2) {
    int e = blockIdx.x * blockDim.x + threadIdx.x;
    if (e >= N_EDGES) return;
    if (ei[N_EDGES + e] == 0) {            // dst == 0
        int s = ei[e];
        need2[s] = 1; need1[s] = 1; need0[s] = 1;
    }
}

__global__ void k_mark1(const int* __restrict__ ei, const int* __restrict__ need2,
                        int* need1, int* need0) {
    int e = blockIdx.x * blockDim.x + threadIdx.x;
    if (e >= N_EDGES) return;
    int d = ei[N_EDGES + e];
    if (need2[d]) { int s = ei[e]; need1[s] = 1; need0[s] = 1; }
}

__global__ void k_mark0(const int* __restrict__ ei, const int* __restrict__ need1, int* need0) {
    int e = blockIdx.x * blockDim.x + threadIdx.x;
    if (e >= N_EDGES) return;
    int d = ei[N_EDGES + e];
    if (need1[d]) need0[ei[e]] = 1;
}

__global__ void k_compact_nodes(const int* __restrict__ need0, const int* __restrict__ need1,
                                const int* __restrict__ need2,
                                int* list0, int* list1, int* list2, int* list3, int* cnt) {
    int i = blockIdx.x * blockDim.x + threadIdx.x;
    if (i == 0) { list3[0] = 0; cnt[6] = 1; }
    if (i >= N_NODES) return;
    if (need0[i]) list0[atomicAdd(&cnt[0], 1)] = i;
    if (need1[i]) list1[atomicAdd(&cnt[1], 1)] = i;
    if (need2[i]) list2[atomicAdd(&cnt[2], 1)] = i;
}

__global__ void k_compact_edges(const int* __restrict__ ei, const int* __restrict__ need1,
                                const int* __restrict__ need2,
                                int* el1, int* el2, int* el3, int* cnt) {
    int e = blockIdx.x * blockDim.x + threadIdx.x;
    if (e >= N_EDGES) return;
    int d = ei[N_EDGES + e];
    int s = ei[e];
    if (need1[d]) { int p = atomicAdd(&cnt[3], 1); if (p < ELIST_CAP) { el1[2*p] = s; el1[2*p+1] = d; } }
    if (need2[d]) { int p = atomicAdd(&cnt[4], 1); if (p < ELIST_CAP) { el2[2*p] = s; el2[2*p+1] = d; } }
    if (d == 0)   { int p = atomicAdd(&cnt[5], 1); if (p < ELIST_CAP) { el3[2*p] = s; el3[2*p+1] = d; } }
}

// ---------- node encoder: h0 = LN(relu(x @ Wn + bn)) on list0 ----------
__global__ void k_encoder(const float* __restrict__ x, const float* __restrict__ Wn,
                          const float* __restrict__ bn, const float* __restrict__ gn,
                          const float* __restrict__ betan,
                          const int* __restrict__ list0, const int* __restrict__ cnt,
                          float* __restrict__ h) {
    int gtid = blockIdx.x * blockDim.x + threadIdx.x;
    int wid = gtid >> 6, lane = gtid & 63;
    int nw = (gridDim.x * blockDim.x) >> 6;
    int n0 = cnt[0];
    for (int w = wid; w < n0; w += nw) {
        int i = list0[w];
        float acc = bn[lane];
        #pragma unroll
        for (int k = 0; k < FN_DIM; k++) acc += x[i * FN_DIM + k] * Wn[k * HD + lane];
        float v = fmaxf(acc, 0.f);
        float mu = wsum64(v) * (1.f / 64.f);
        float d = v - mu;
        float var = wsum64(d * d) * (1.f / 64.f);
        h[i * HD + lane] = d * rsqrtf(var + 1e-5f) * gn[lane] + betan[lane];
    }
}

// ---------- per-layer GAT precompute: xg = h@Wg, a_s, a_d on active list ----------
__global__ void k_xg(const float* __restrict__ h, const float* __restrict__ Wg,
                     const float* __restrict__ atts, const float* __restrict__ attd,
                     const int* __restrict__ list, const int* __restrict__ cnt, int cidx,
                     float* __restrict__ xg, float* __restrict__ a_s, float* __restrict__ a_d) {
    int gtid = blockIdx.x * blockDim.x + threadIdx.x;
    int wid = gtid >> 6, lane = gtid & 63;
    int nw = (gridDim.x * blockDim.x) >> 6;
    int n = cnt[cidx];
    for (int w = wid; w < n; w += nw) {
        int i = list[w];
        float hv = h[i * HD + lane];
        float acc = 0.f;
        #pragma unroll
        for (int k = 0; k < HD; k++) acc += __shfl(hv, k) * Wg[k * HD + lane];
        xg[i * HD + lane] = acc;
        float s = wsum64(acc * atts[lane]);
        float dd = wsum64(acc * attd[lane]);
        if (lane == 0) { a_s[i] = s; a_d[i] = dd; }
    }
}

// ---------- per-layer fused EdgeConv(max) + GAT + residual relu ----------
__global__ __launch_bounds__(256) void k_layer(
    const float* __restrict__ h, const float* __restrict__ xg,
    const float* __restrict__ a_s, const float* __restrict__ a_d,
    const float* __restrict__ Wc1, const float* __restrict__ bc1,
    const float* __restrict__ Wc2, const float* __restrict__ bc2,
    const float* __restrict__ bg,
    const int* __restrict__ tlist, const int* __restrict__ cnt, int tcnt_idx,
    const int* __restrict__ elist, int ecnt_idx,
    float* __restrict__ hout)
{
    __shared__ float wc1s[128 * 64];
    __shared__ float wc2s[64 * 64];
    __shared__ float bc1s[64], bc2s[64], bgs[64];
    for (int idx = threadIdx.x; idx < 128 * 64; idx += blockDim.x) wc1s[idx] = Wc1[idx];
    for (int idx = threadIdx.x; idx < 64 * 64; idx += blockDim.x) wc2s[idx] = Wc2[idx];
    if (threadIdx.x < 64) {
        bc1s[threadIdx.x] = bc1[threadIdx.x];
        bc2s[threadIdx.x] = bc2[threadIdx.x];
        bgs[threadIdx.x]  = bg[threadIdx.x];
    }
    __syncthreads();

    int gtid = blockIdx.x * blockDim.x + threadIdx.x;
    int wid = gtid >> 6, lane = gtid & 63;
    int nw = (gridDim.x * blockDim.x) >> 6;
    int ntgt = cnt[tcnt_idx];
    int ne = cnt[ecnt_idx]; if (ne > ELIST_CAP) ne = ELIST_CAP;

    for (int w = wid; w < ntgt; w += nw) {
        int t = tlist[w];
        float htv = h[t * HD + lane];          // h[target][lane]
        float adt = a_d[t];
        float e_self = lrelu02(a_s[t] + adt);  // GAT self-loop

        // ---- pass 1: segment max of e over edges with dst==t (incl self)
        float em = e_self;
        for (int base = 0; base < ne; base += 64) {
            int idx = base + lane;
            float ev = -INFINITY;
            if (idx < ne && elist[2 * idx + 1] == t)
                ev = lrelu02(a_s[elist[2 * idx]] + adt);
            em = fmaxf(em, ev);
        }
        em = wmax64(em);

        // ---- pass 2: EdgeConv MLP + max, GAT exp-weighted sums
        float wpart = 0.f;      // per-lane partial of sum(w)
        float attacc = 0.f;     // per-lane (=channel) sum of w * xg[src]
        float aggmax = -INFINITY;
        for (int base = 0; base < ne; base += 64) {
            int idx = base + lane;
            int s = -1; float wv = 0.f;
            if (idx < ne && elist[2 * idx + 1] == t) {
                s = elist[2 * idx];
                wv = expf(lrelu02(a_s[s] + adt) - em);
            }
            wpart += wv;
            unsigned long long mask = __ballot(s >= 0);
            while (mask) {
                int b = __ffsll(mask) - 1; mask &= mask - 1;
                int sb = __shfl(s, b);
                float wb = __shfl(wv, b);
                attacc += wb * xg[sb * HD + lane];
                // EdgeConv message MLP: relu(concat(h[t],h[src]) @ Wc1 + bc1) @ Wc2 + bc2
                float hsv = h[sb * HD + lane];
                float acc1 = bc1s[lane];
                #pragma unroll
                for (int k = 0; k < 64; k++) acc1 += __shfl(htv, k) * wc1s[k * 64 + lane];
                #pragma unroll
                for (int k = 0; k < 64; k++) acc1 += __shfl(hsv, k) * wc1s[(64 + k) * 64 + lane];
                float hid = fmaxf(acc1, 0.f);
                float acc2 = bc2s[lane];
                #pragma unroll
                for (int k = 0; k < 64; k++) acc2 += __shfl(hid, k) * wc2s[k * 64 + lane];
                aggmax = fmaxf(aggmax, acc2);
            }
        }
        float wself = expf(e_self - em);
        float wsum = wsum64(wpart) + wself;
        attacc += wself * xg[t * HD + lane];
        float att = attacc / wsum + bgs[lane];
        float agg = (aggmax == -INFINITY) ? 0.f : aggmax;   // PyG: empty segment -> 0
        hout[t * HD + lane] = fmaxf(htv + agg + att, 0.f);
    }
}

// ---------- heads on h[0] ----------
__global__ void k_heads(const float* __restrict__ h,
                        const float* __restrict__ Wq1, const float* __restrict__ bq1,
                        const float* __restrict__ gq, const float* __restrict__ betaq,
                        const float* __restrict__ Wq2, const float* __restrict__ bq2,
                        const float* __restrict__ Wv1, const float* __restrict__ bv1,
                        const float* __restrict__ gv, const float* __restrict__ betav,
                        const float* __restrict__ Wv2, const float* __restrict__ bv2,
                        float* __restrict__ out) {
    int lane = threadIdx.x & 63;
    float t = h[lane];
    // q head
    float acc = bq1[lane];
    #pragma unroll
    for (int k = 0; k < 64; k++) acc += __shfl(t, k) * Wq1[k * 64 + lane];
    float r = fmaxf(acc, 0.f);
    float mu = wsum64(r) * (1.f / 64.f);
    float d = r - mu;
    float var = wsum64(d * d) * (1.f / 64.f);
    float tq = d * rsqrtf(var + 1e-5f) * gq[lane] + betaq[lane];
    // v head
    float accv = bv1[lane];
    #pragma unroll
    for (int k = 0; k < 64; k++) accv += __shfl(t, k) * Wv1[k * 64 + lane];
    float rv = fmaxf(accv, 0.f);
    float muv = wsum64(rv) * (1.f / 64.f);
    float dv = rv - muv;
    float varv = wsum64(dv * dv) * (1.f / 64.f);
    float tv = dv * rsqrtf(varv + 1e-5f) * gv[lane] + betav[lane];
    // q outputs (compute on all lanes with s=lane&31, write lanes <32)
    int s = lane & 31;
    float q = bq2[s];
    #pragma unroll
    for (int k = 0; k < 64; k++) q += __shfl(tq, k) * Wq2[k * 32 + s];
    if (lane < 32) out[lane] = q;
    // value output
    float vsum = wsum64(tv * Wv2[lane]);
    if (lane == 0) out[32] = vsum + bv2[0];
}

extern "C" void kernel_launch(void* const* d_in, const int* in_sizes, int n_in,
                              void* d_out, int out_size, void* d_ws, size_t ws_size,
                              hipStream_t stream) {
    const float* x        = (const float*)d_in[0];
    const int*   ei       = (const int*)d_in[1];
    // d_in[2] edge_attr and d_in[7..10] (edge encoder) are dead code in the reference
    const float* Wn       = (const float*)d_in[3];
    const float* bn       = (const float*)d_in[4];
    const float* gn       = (const float*)d_in[5];
    const float* betan    = (const float*)d_in[6];
    const float* Wc1      = (const float*)d_in[11];
    const float* bc1      = (const float*)d_in[12];
    const float* Wc2      = (const float*)d_in[13];
    const float* bc2      = (const float*)d_in[14];
    const float* Wg       = (const float*)d_in[15];
    const float* att_src  = (const float*)d_in[16];
    const float* att_dst  = (const float*)d_in[17];
    const float* bg       = (const float*)d_in[18];
    const float* Wq1      = (const float*)d_in[19];
    const float* bq1      = (const float*)d_in[20];
    const float* gq       = (const float*)d_in[21];
    const float* betaq    = (const float*)d_in[22];
    const float* Wq2      = (const float*)d_in[23];
    const float* bq2      = (const float*)d_in[24];
    const float* Wv1      = (const float*)d_in[25];
    const float* bv1      = (const float*)d_in[26];
    const float* gv       = (const float*)d_in[27];
    const float* betav    = (const float*)d_in[28];
    const float* Wv2      = (const float*)d_in[29];
    const float* bv2      = (const float*)d_in[30];

    // workspace layout
    float* hA   = (float*)d_ws;                 // N*64
    float* hB   = hA + (size_t)N_NODES * HD;    // N*64
    float* xg   = hB + (size_t)N_NODES * HD;    // N*64
    float* a_s  = xg + (size_t)N_NODES * HD;    // N
    float* a_d  = a_s + N_NODES;                // N
    int* need0  = (int*)(a_d + N_NODES);        // N
    int* need1  = need0 + N_NODES;
    int* need2  = need1 + N_NODES;
    int* list0  = need2 + N_NODES;
    int* list1  = list0 + N_NODES;
    int* list2  = list1 + N_NODES;
    int* list3  = list2 + N_NODES;              // 16 ints
    int* el1    = list3 + 16;                   // ELIST_CAP*2
    int* el2    = el1 + (size_t)ELIST_CAP * 2;
    int* el3    = el2 + (size_t)ELIST_CAP * 2;
    int* cnt    = el3 + (size_t)ELIST_CAP * 2;  // 32 ints

    const int EB = (N_EDGES + 255) / 256;       // 3125 blocks
    const int NB = (N_NODES + 255) / 256;       // 196 blocks

    k_init<<<NB, 256, 0, stream>>>(need0, need1, need2, cnt);
    k_mark2<<<EB, 256, 0, stream>>>(ei, need0, need1, need2);
    k_mark1<<<EB, 256, 0, stream>>>(ei, need2, need1, need0);
    k_mark0<<<EB, 256, 0, stream>>>(ei, need1, need0);
    k_compact_nodes<<<NB, 256, 0, stream>>>(need0, need1, need2, list0, list1, list2, list3, cnt);
    k_compact_edges<<<EB, 256, 0, stream>>>(ei, need1, need2, el1, el2, el3, cnt);
    k_encoder<<<512, 256, 0, stream>>>(x, Wn, bn, gn, betan, list0, cnt, hA);

    for (int l = 0; l < NL; l++) {
        const float* hin  = (l == 0) ? hA : (l == 1) ? hB : hA;
        float*       hout = (l == 0) ? hB : (l == 1) ? hA : hB;
        const int* alist  = (l == 0) ? list0 : (l == 1) ? list1 : list2;
        int acnt_idx      = l;                         // cnt[0], cnt[1], cnt[2]
        const int* tlist  = (l == 0) ? list1 : (l == 1) ? list2 : list3;
        int tcnt_idx      = (l == 0) ? 1 : (l == 1) ? 2 : 6;
        const int* el     = (l == 0) ? el1 : (l == 1) ? el2 : el3;
        int ecnt_idx      = 3 + l;

        k_xg<<<256, 256, 0, stream>>>(hin, Wg + l * HD * HD, att_src + l * HD, att_dst + l * HD,
                                      alist, cnt, acnt_idx, xg, a_s, a_d);
        k_layer<<<128, 256, 0, stream>>>(hin, xg, a_s, a_d,
                                         Wc1 + l * 2 * HD * HD, bc1 + l * HD,
                                         Wc2 + l * HD * HD, bc2 + l * HD, bg + l * HD,
                                         tlist, cnt, tcnt_idx, el, ecnt_idx, hout);
    }

    k_heads<<<1, 64, 0, stream>>>(hB, Wq1, bq1, gq, betaq, Wq2, bq2,
                                  Wv1, bv1, gv, betav, Wv2, bv2, (float*)d_out);
}

// Round 2
// 284.328 us; speedup vs baseline: 2.2912x; 2.2912x over previous
//
#include <hip/hip_runtime.h>
#include <math.h>

// Problem constants (fixed by the reference)
#define N_NODES 50000
#define N_EDGES 800000
#define FN_DIM 16
#define HD 64
#define NL 3
#define S_CAP 16384    // cap on |need0| (expected ~4.9k)
#define T_CAP 8192     // cap on |need1| (expected ~290)
#define T2_CAP 512     // cap on |need2| (expected ~17)
#define MAXDEG 128     // cap on in-degree (Poisson(16), P(>128) ~ 0)

// ---------- wave-64 helpers ----------
__device__ __forceinline__ float wsum64(float v) {
    #pragma unroll
    for (int o = 1; o < 64; o <<= 1) v += __shfl_xor(v, o);
    return v;
}
__device__ __forceinline__ float wmax64(float v) {
    #pragma unroll
    for (int o = 1; o < 64; o <<= 1) v = fmaxf(v, __shfl_xor(v, o));
    return v;
}
__device__ __forceinline__ float lrelu02(float v) { return v > 0.f ? v : 0.2f * v; }

// ---------- init: need flags, counters, degree counters ----------
__global__ void k_init(int* need0, int* need1, int* need2, int* cnt,
                       int* deg1, int* deg2, int* deg3, int* list3) {
    int i = blockIdx.x * blockDim.x + threadIdx.x;
    if (i < N_NODES) { int v = (i == 0) ? 1 : 0; need0[i] = v; need1[i] = v; need2[i] = v; }
    if (i < 32) cnt[i] = (i == 6) ? 1 : 0;   // cnt[6] = ntgt for layer 2 (node 0)
    if (i < T_CAP)  deg1[i] = 0;
    if (i < T2_CAP) deg2[i] = 0;
    if (i == 0) { deg3[0] = 0; list3[0] = 0; }
}

// ---------- backward BFS marking (3 levels) ----------
__global__ void k_mark2(const int* __restrict__ ei, int* need0, int* need1, int* need2) {
    int e = blockIdx.x * blockDim.x + threadIdx.x;
    if (e >= N_EDGES) return;
    if (ei[N_EDGES + e] == 0) { int s = ei[e]; need2[s] = 1; need1[s] = 1; need0[s] = 1; }
}
__global__ void k_mark1(const int* __restrict__ ei, const int* __restrict__ need2,
                        int* need1, int* need0) {
    int e = blockIdx.x * blockDim.x + threadIdx.x;
    if (e >= N_EDGES) return;
    int d = ei[N_EDGES + e];
    if (need2[d]) { int s = ei[e]; need1[s] = 1; need0[s] = 1; }
}
__global__ void k_mark0(const int* __restrict__ ei, const int* __restrict__ need1, int* need0) {
    int e = blockIdx.x * blockDim.x + threadIdx.x;
    if (e >= N_EDGES) return;
    if (need1[ei[N_EDGES + e]]) need0[ei[e]] = 1;
}

// ---------- compact node lists + node->compact-index maps ----------
__global__ void k_compact_nodes(const int* __restrict__ need0, const int* __restrict__ need1,
                                const int* __restrict__ need2,
                                int* list0, int* list1, int* list2,
                                int* idx0, int* idx1, int* idx2, int* cnt) {
    int i = blockIdx.x * blockDim.x + threadIdx.x;
    if (i >= N_NODES) return;
    if (need0[i]) { int p = atomicAdd(&cnt[0], 1); if (p < S_CAP)  { list0[p] = i; idx0[i] = p; } }
    if (need1[i]) { int p = atomicAdd(&cnt[1], 1); if (p < T_CAP)  { list1[p] = i; idx1[i] = p; } }
    if (need2[i]) { int p = atomicAdd(&cnt[2], 1); if (p < T2_CAP) { list2[p] = i; idx2[i] = p; } }
}

// ---------- CSR buckets: per-target edge lists (store SOURCE compact idx) ----------
__global__ void k_bucket(const int* __restrict__ ei, const int* __restrict__ need1,
                         const int* __restrict__ need2,
                         const int* __restrict__ idx0, const int* __restrict__ idx1,
                         const int* __restrict__ idx2,
                         int* eb1, int* deg1, int* eb2, int* deg2, int* eb3, int* deg3) {
    int e = blockIdx.x * blockDim.x + threadIdx.x;
    if (e >= N_EDGES) return;
    int d = ei[N_EDGES + e];
    int s = ei[e];
    if (need1[d]) {
        int t = idx1[d];
        if ((unsigned)t < T_CAP) { int p = atomicAdd(&deg1[t], 1); if (p < MAXDEG) eb1[t * MAXDEG + p] = idx0[s]; }
    }
    if (need2[d]) {
        int t = idx2[d];
        if ((unsigned)t < T2_CAP) { int p = atomicAdd(&deg2[t], 1); if (p < MAXDEG) eb2[t * MAXDEG + p] = idx1[s]; }
    }
    if (d == 0) { int p = atomicAdd(deg3, 1); if (p < MAXDEG) eb3[p] = idx2[s]; }
}

// ---------- node encoder: h0 = LN(relu(x @ Wn + bn)) on list0 ----------
__global__ void k_encoder(const float* __restrict__ x, const float* __restrict__ Wn,
                          const float* __restrict__ bn, const float* __restrict__ gn,
                          const float* __restrict__ betan,
                          const int* __restrict__ list0, const int* __restrict__ cnt,
                          float* __restrict__ h) {
    int gtid = blockIdx.x * blockDim.x + threadIdx.x;
    int wid = gtid >> 6, lane = gtid & 63;
    int nw = (gridDim.x * blockDim.x) >> 6;
    int n0 = cnt[0]; if (n0 > S_CAP) n0 = S_CAP;
    for (int w = wid; w < n0; w += nw) {
        int i = list0[w];
        float acc = bn[lane];
        #pragma unroll
        for (int k = 0; k < FN_DIM; k++) acc += x[i * FN_DIM + k] * Wn[k * HD + lane];
        float v = fmaxf(acc, 0.f);
        float mu = wsum64(v) * (1.f / 64.f);
        float d = v - mu;
        float var = wsum64(d * d) * (1.f / 64.f);
        h[i * HD + lane] = d * rsqrtf(var + 1e-5f) * gn[lane] + betan[lane];
    }
}

// ---------- per-layer node precompute over SOURCE list:
//   xg = h@Wg ; a_s, a_d ; u = Wc1[0:64]·h + bc1 (target half) ; v = Wc1[64:128]·h (source half)
__global__ __launch_bounds__(256) void k_prep(const float* __restrict__ h,
    const float* __restrict__ Wg, const float* __restrict__ atts, const float* __restrict__ attd,
    const float* __restrict__ Wc1, const float* __restrict__ bc1,
    const int* __restrict__ list, const int* __restrict__ cnt, int cidx, int cap,
    float* __restrict__ xg_c, float* __restrict__ u_c, float* __restrict__ v_c,
    float* __restrict__ as_c, float* __restrict__ ad_c) {
    int gtid = blockIdx.x * blockDim.x + threadIdx.x;
    int wid = gtid >> 6, lane = gtid & 63;
    int nw = (gridDim.x * blockDim.x) >> 6;
    int n = cnt[cidx]; if (n > cap) n = cap;
    for (int w = wid; w < n; w += nw) {
        int i = list[w];
        float hv = h[i * HD + lane];
        float xg = 0.f, u = bc1[lane], v = 0.f;
        #pragma unroll
        for (int k = 0; k < HD; k++) {
            float b = __shfl(hv, k);
            xg += b * Wg[k * HD + lane];
            u  += b * Wc1[k * HD + lane];
            v  += b * Wc1[(HD + k) * HD + lane];
        }
        xg_c[w * HD + lane] = xg;
        u_c[w * HD + lane]  = u;
        v_c[w * HD + lane]  = v;
        float s  = wsum64(xg * atts[lane]);
        float dd = wsum64(xg * attd[lane]);
        if (lane == 0) { as_c[w] = s; ad_c[w] = dd; }
    }
}

// ---------- per-layer fused EdgeConv(max) + GAT + residual relu, CSR per-target ----------
__global__ __launch_bounds__(256) void k_fused(const float* __restrict__ h,
    const float* __restrict__ xg_c, const float* __restrict__ u_c, const float* __restrict__ v_c,
    const float* __restrict__ as_c, const float* __restrict__ ad_c,
    const float* __restrict__ Wc2, const float* __restrict__ bc2, const float* __restrict__ bg,
    const int* __restrict__ tlist, const int* __restrict__ cnt, int tcidx, int tcap,
    const int* __restrict__ idxmap, const int* __restrict__ eb, const int* __restrict__ deg,
    float* __restrict__ hout) {
    __shared__ float wc2s[HD * HD];
    __shared__ float bc2s[HD], bgs[HD];
    for (int idx = threadIdx.x; idx < HD * HD; idx += blockDim.x) wc2s[idx] = Wc2[idx];
    if (threadIdx.x < HD) { bc2s[threadIdx.x] = bc2[threadIdx.x]; bgs[threadIdx.x] = bg[threadIdx.x]; }
    __syncthreads();

    int gtid = blockIdx.x * blockDim.x + threadIdx.x;
    int wid = gtid >> 6, lane = gtid & 63;
    int nw = (gridDim.x * blockDim.x) >> 6;
    int ntgt = cnt[tcidx]; if (ntgt > tcap) ntgt = tcap;

    for (int w = wid; w < ntgt; w += nw) {
        int t = tlist[w];
        int st = idxmap[t];                 // target's index in the SOURCE compact space
        float ht = h[t * HD + lane];
        float urow = u_c[st * HD + lane];
        float adt = ad_c[st];
        int dg = deg[w]; if (dg > MAXDEG) dg = MAXDEG;

        // ---- EdgeConv: m_e = Wc2·relu(u_t + v_s) + bc2, segment-max over edges
        float aggmax = -INFINITY;
        for (int j = 0; j < dg; j++) {
            int sp = eb[w * MAXDEG + j];
            float hid = fmaxf(urow + v_c[sp * HD + lane], 0.f);
            float acc = bc2s[lane];
            #pragma unroll
            for (int k = 0; k < HD; k++) acc += __shfl(hid, k) * wc2s[k * HD + lane];
            aggmax = fmaxf(aggmax, acc);
        }

        // ---- GAT: softmax over in-edges + self-loop
        float es = lrelu02(as_c[st] + adt);
        float em = es;
        for (int base = 0; base < dg; base += 64) {
            int j = base + lane;
            float ev = -INFINITY;
            if (j < dg) { int sp = eb[w * MAXDEG + j]; ev = lrelu02(as_c[sp] + adt); }
            em = fmaxf(em, ev);
        }
        em = wmax64(em);

        float wpart = 0.f, attacc = 0.f;
        for (int base = 0; base < dg; base += 64) {
            int j = base + lane;
            int sp = 0; float wv = 0.f;
            if (j < dg) { sp = eb[w * MAXDEG + j]; wv = expf(lrelu02(as_c[sp] + adt) - em); }
            wpart += wv;
            int m = dg - base; if (m > 64) m = 64;
            for (int q = 0; q < m; q++) {
                int spq = __shfl(sp, q);
                float wq = __shfl(wv, q);
                attacc += wq * xg_c[spq * HD + lane];
            }
        }
        float wself = expf(es - em);
        float wsumv = wsum64(wpart) + wself;
        attacc += wself * xg_c[st * HD + lane];

        float agg = (aggmax == -INFINITY) ? 0.f : aggmax;   // PyG: empty segment -> 0
        hout[t * HD + lane] = fmaxf(ht + agg + attacc / wsumv + bgs[lane], 0.f);
    }
}

// ---------- heads on h[0] ----------
__global__ void k_heads(const float* __restrict__ h,
                        const float* __restrict__ Wq1, const float* __restrict__ bq1,
                        const float* __restrict__ gq, const float* __restrict__ betaq,
                        const float* __restrict__ Wq2, const float* __restrict__ bq2,
                        const float* __restrict__ Wv1, const float* __restrict__ bv1,
                        const float* __restrict__ gv, const float* __restrict__ betav,
                        const float* __restrict__ Wv2, const float* __restrict__ bv2,
                        float* __restrict__ out) {
    int lane = threadIdx.x & 63;
    float t = h[lane];
    float acc = bq1[lane];
    #pragma unroll
    for (int k = 0; k < 64; k++) acc += __shfl(t, k) * Wq1[k * 64 + lane];
    float r = fmaxf(acc, 0.f);
    float mu = wsum64(r) * (1.f / 64.f);
    float d = r - mu;
    float var = wsum64(d * d) * (1.f / 64.f);
    float tq = d * rsqrtf(var + 1e-5f) * gq[lane] + betaq[lane];
    float accv = bv1[lane];
    #pragma unroll
    for (int k = 0; k < 64; k++) accv += __shfl(t, k) * Wv1[k * 64 + lane];
    float rv = fmaxf(accv, 0.f);
    float muv = wsum64(rv) * (1.f / 64.f);
    float dv = rv - muv;
    float varv = wsum64(dv * dv) * (1.f / 64.f);
    float tv = dv * rsqrtf(varv + 1e-5f) * gv[lane] + betav[lane];
    int s = lane & 31;
    float q = bq2[s];
    #pragma unroll
    for (int k = 0; k < 64; k++) q += __shfl(tq, k) * Wq2[k * 32 + s];
    if (lane < 32) out[lane] = q;
    float vsum = wsum64(tv * Wv2[lane]);
    if (lane == 0) out[32] = vsum + bv2[0];
}

extern "C" void kernel_launch(void* const* d_in, const int* in_sizes, int n_in,
                              void* d_out, int out_size, void* d_ws, size_t ws_size,
                              hipStream_t stream) {
    const float* x        = (const float*)d_in[0];
    const int*   ei       = (const int*)d_in[1];
    // d_in[2] edge_attr and d_in[7..10] (edge encoder) are dead code in the reference
    const float* Wn       = (const float*)d_in[3];
    const float* bn       = (const float*)d_in[4];
    const float* gn       = (const float*)d_in[5];
    const float* betan    = (const float*)d_in[6];
    const float* Wc1      = (const float*)d_in[11];
    const float* bc1      = (const float*)d_in[12];
    const float* Wc2      = (const float*)d_in[13];
    const float* bc2      = (const float*)d_in[14];
    const float* Wg       = (const float*)d_in[15];
    const float* att_src  = (const float*)d_in[16];
    const float* att_dst  = (const float*)d_in[17];
    const float* bg       = (const float*)d_in[18];
    const float* Wq1      = (const float*)d_in[19];
    const float* bq1      = (const float*)d_in[20];
    const float* gq       = (const float*)d_in[21];
    const float* betaq    = (const float*)d_in[22];
    const float* Wq2      = (const float*)d_in[23];
    const float* bq2      = (const float*)d_in[24];
    const float* Wv1      = (const float*)d_in[25];
    const float* bv1      = (const float*)d_in[26];
    const float* gv       = (const float*)d_in[27];
    const float* betav    = (const float*)d_in[28];
    const float* Wv2      = (const float*)d_in[29];
    const float* bv2      = (const float*)d_in[30];

    // ---- workspace layout (~44 MB)
    float* hA   = (float*)d_ws;                      // N*64
    float* hB   = hA + (size_t)N_NODES * HD;         // N*64
    float* xg_c = hB + (size_t)N_NODES * HD;         // S_CAP*64
    float* u_c  = xg_c + (size_t)S_CAP * HD;         // S_CAP*64
    float* v_c  = u_c + (size_t)S_CAP * HD;          // S_CAP*64
    float* as_c = v_c + (size_t)S_CAP * HD;          // S_CAP
    float* ad_c = as_c + S_CAP;                      // S_CAP
    int* need0  = (int*)(ad_c + S_CAP);              // N
    int* need1  = need0 + N_NODES;
    int* need2  = need1 + N_NODES;
    int* idx0   = need2 + N_NODES;                   // N
    int* idx1   = idx0 + N_NODES;
    int* idx2   = idx1 + N_NODES;
    int* list0  = idx2 + N_NODES;                    // S_CAP
    int* list1  = list0 + S_CAP;                     // T_CAP
    int* list2  = list1 + T_CAP;                     // T2_CAP
    int* list3  = list2 + T2_CAP;                    // 4
    int* eb1    = list3 + 4;                         // T_CAP*MAXDEG
    int* deg1   = eb1 + (size_t)T_CAP * MAXDEG;      // T_CAP
    int* eb2    = deg1 + T_CAP;                      // T2_CAP*MAXDEG
    int* deg2   = eb2 + (size_t)T2_CAP * MAXDEG;     // T2_CAP
    int* eb3    = deg2 + T2_CAP;                     // MAXDEG
    int* deg3   = eb3 + MAXDEG;                      // 4
    int* cnt    = deg3 + 4;                          // 32

    const int EB = (N_EDGES + 255) / 256;            // 3125 blocks
    const int NB = (N_NODES + 255) / 256;            // 196 blocks

    k_init<<<NB, 256, 0, stream>>>(need0, need1, need2, cnt, deg1, deg2, deg3, list3);
    k_mark2<<<EB, 256, 0, stream>>>(ei, need0, need1, need2);
    k_mark1<<<EB, 256, 0, stream>>>(ei, need2, need1, need0);
    k_mark0<<<EB, 256, 0, stream>>>(ei, need1, need0);
    k_compact_nodes<<<NB, 256, 0, stream>>>(need0, need1, need2, list0, list1, list2,
                                            idx0, idx1, idx2, cnt);
    k_bucket<<<EB, 256, 0, stream>>>(ei, need1, need2, idx0, idx1, idx2,
                                     eb1, deg1, eb2, deg2, eb3, deg3);
    k_encoder<<<256, 256, 0, stream>>>(x, Wn, bn, gn, betan, list0, cnt, hA);

    for (int l = 0; l < NL; l++) {
        const float* hin  = (l == 0) ? hA : (l == 1) ? hB : hA;
        float*       hout = (l == 0) ? hB : (l == 1) ? hA : hB;
        const int* slist  = (l == 0) ? list0 : (l == 1) ? list1 : list2;
        int scap          = (l == 0) ? S_CAP : (l == 1) ? T_CAP : T2_CAP;
        const int* tlist  = (l == 0) ? list1 : (l == 1) ? list2 : list3;
        int tcidx         = (l == 0) ? 1 : (l == 1) ? 2 : 6;
        int tcap          = (l == 0) ? T_CAP : (l == 1) ? T2_CAP : 1;
        const int* imap   = (l == 0) ? idx0 : (l == 1) ? idx1 : idx2;
        const int* eb     = (l == 0) ? eb1 : (l == 1) ? eb2 : eb3;
        const int* deg    = (l == 0) ? deg1 : (l == 1) ? deg2 : deg3;

        k_prep<<<256, 256, 0, stream>>>(hin, Wg + l * HD * HD, att_src + l * HD, att_dst + l * HD,
                                        Wc1 + l * 2 * HD * HD, bc1 + l * HD,
                                        slist, cnt, l, scap,
                                        xg_c, u_c, v_c, as_c, ad_c);
        k_fused<<<128, 256, 0, stream>>>(hin, xg_c, u_c, v_c, as_c, ad_c,
                                         Wc2 + l * HD * HD, bc2 + l * HD, bg + l * HD,
                                         tlist, cnt, tcidx, tcap, imap, eb, deg, hout);
    }

    k_heads<<<1, 64, 0, stream>>>(hB, Wq1, bq1, gq, betaq, Wq2, bq2,
                                  Wv1, bv1, gv, betav, Wv2, bv2, (float*)d_out);
}

// Round 3
// 98.356 us; speedup vs baseline: 6.6234x; 2.8908x over previous
//
#include <hip/hip_runtime.h>
#include <math.h>

// Problem constants (fixed by the reference)
#define N_NODES 50000
#define N_EDGES 800000
#define FN_DIM 16
#define HD 64
#define T_CAP 8192     // cap on |need1| (expected ~290)  = layer-0 targets
#define T2_CAP 512     // cap on |need2| (expected ~17)   = layer-1 targets
#define MAXDEG 128     // cap on in-degree (Poisson(16))

// ---------- wave-64 helpers ----------
__device__ __forceinline__ float wsum64(float v) {
    #pragma unroll
    for (int o = 1; o < 64; o <<= 1) v += __shfl_xor(v, o);
    return v;
}
__device__ __forceinline__ float wmax64(float v) {
    #pragma unroll
    for (int o = 1; o < 64; o <<= 1) v = fmaxf(v, __shfl_xor(v, o));
    return v;
}
__device__ __forceinline__ float lrelu02(float v) { return v > 0.f ? v : 0.2f * v; }

// ---------- discovery ----------
__global__ void k_mark2(const int* __restrict__ ei, int* need1, int* need2) {
    int e = blockIdx.x * blockDim.x + threadIdx.x;
    if (e == 0) { need1[0] = 1; need2[0] = 1; }
    if (e >= N_EDGES) return;
    if (ei[N_EDGES + e] == 0) { int s = ei[e]; need2[s] = 1; need1[s] = 1; }
}
__global__ void k_mark1(const int* __restrict__ ei, const int* __restrict__ need2, int* need1) {
    int e = blockIdx.x * blockDim.x + threadIdx.x;
    if (e >= N_EDGES) return;
    if (need2[ei[N_EDGES + e]]) need1[ei[e]] = 1;
}
__global__ void k_compact(const int* __restrict__ need1, const int* __restrict__ need2,
                          int* list1, int* list2, int* idx1, int* idx2, int* cnt) {
    int i = blockIdx.x * blockDim.x + threadIdx.x;
    if (i >= N_NODES) return;
    if (need1[i]) { int p = atomicAdd(&cnt[0], 1); if (p < T_CAP)  { list1[p] = i; idx1[i] = p; } }
    if (need2[i]) { int p = atomicAdd(&cnt[1], 1); if (p < T2_CAP) { list2[p] = i; idx2[i] = p; } }
}
__global__ void k_bucket(const int* __restrict__ ei, const int* __restrict__ need1,
                         const int* __restrict__ need2,
                         const int* __restrict__ idx1, const int* __restrict__ idx2,
                         int* eb1, int* deg1, int* eb2, int* deg2, int* eb3, int* deg3) {
    int e = blockIdx.x * blockDim.x + threadIdx.x;
    if (e >= N_EDGES) return;
    int d = ei[N_EDGES + e];
    int s = ei[e];
    if (need1[d]) {
        int t = idx1[d];
        if ((unsigned)t < T_CAP) { int p = atomicAdd(&deg1[t], 1); if (p < MAXDEG) eb1[t * MAXDEG + p] = s; }
    }
    if (need2[d]) {
        int t = idx2[d];
        if ((unsigned)t < T2_CAP) { int p = atomicAdd(&deg2[t], 1); if (p < MAXDEG) eb2[t * MAXDEG + p] = s; }
    }
    if (d == 0) { int p = atomicAdd(deg3, 1); if (p < MAXDEG) eb3[p] = s; }
}

// ---------- node feature: layer 0 encodes from x, later layers load h ----------
template<int LM>
__device__ __forceinline__ float node_h(int i, int lane,
    const float* __restrict__ x, const float* __restrict__ Wn, const float* __restrict__ bn,
    const float* __restrict__ gn, const float* __restrict__ betan,
    const float* __restrict__ hin) {
    if (LM == 0) {
        float acc = bn[lane];
        #pragma unroll
        for (int k = 0; k < FN_DIM; k++) acc += x[i * FN_DIM + k] * Wn[k * HD + lane];
        float v = fmaxf(acc, 0.f);
        float mu = wsum64(v) * (1.f / 64.f);
        float d = v - mu;
        float var = wsum64(d * d) * (1.f / 64.f);
        return d * rsqrtf(var + 1e-5f) * gn[lane] + betan[lane];
    } else {
        return hin[i * HD + lane];
    }
}

// ---------- heads (wave 0 only), writes out[0..32] ----------
__device__ __forceinline__ void heads_eval(float hv, int lane,
    const float* __restrict__ Wq1, const float* __restrict__ bq1,
    const float* __restrict__ gq, const float* __restrict__ betaq,
    const float* __restrict__ Wq2, const float* __restrict__ bq2,
    const float* __restrict__ Wv1, const float* __restrict__ bv1,
    const float* __restrict__ gv, const float* __restrict__ betav,
    const float* __restrict__ Wv2, const float* __restrict__ bv2,
    float* __restrict__ out) {
    float acc = bq1[lane];
    #pragma unroll 8
    for (int k = 0; k < 64; k++) acc += __shfl(hv, k) * Wq1[k * 64 + lane];
    float r = fmaxf(acc, 0.f);
    float mu = wsum64(r) * (1.f / 64.f);
    float d = r - mu;
    float var = wsum64(d * d) * (1.f / 64.f);
    float tq = d * rsqrtf(var + 1e-5f) * gq[lane] + betaq[lane];
    float accv = bv1[lane];
    #pragma unroll 8
    for (int k = 0; k < 64; k++) accv += __shfl(hv, k) * Wv1[k * 64 + lane];
    float rv = fmaxf(accv, 0.f);
    float muv = wsum64(rv) * (1.f / 64.f);
    float dv = rv - muv;
    float varv = wsum64(dv * dv) * (1.f / 64.f);
    float tv = dv * rsqrtf(varv + 1e-5f) * gv[lane] + betav[lane];
    int s = lane & 31;
    float q = bq2[s];
    #pragma unroll 8
    for (int k = 0; k < 64; k++) q += __shfl(tq, k) * Wq2[k * 32 + s];
    if (lane < 32) out[lane] = q;
    float vsum = wsum64(tv * Wv2[lane]);
    if (lane == 0) out[32] = vsum + bv2[0];
}

// ---------- fully fused layer: block per target, 4 waves edge-parallel ----------
// EdgeConv: m = Wc2.relu(Wc1a.h_t + Wc1b.h_s + bc1) + bc2, segment-max
// GAT: softmax over in-edges + self-loop of lrelu(a_s[src]+a_d[t]), weighted sum of xg
// out: h' = relu(h_t + agg + att + bg)
template<int LM>
__global__ __launch_bounds__(256) void k_layer(
    const float* __restrict__ x, const float* __restrict__ Wn, const float* __restrict__ bn,
    const float* __restrict__ gn, const float* __restrict__ betan,
    const float* __restrict__ hin,
    const float* __restrict__ Wc1, const float* __restrict__ bc1,
    const float* __restrict__ Wc2, const float* __restrict__ bc2,
    const float* __restrict__ Wg, const float* __restrict__ atts, const float* __restrict__ attd,
    const float* __restrict__ bgv,
    const int* __restrict__ tlist, const int* __restrict__ cntp, int tcap,
    const int* __restrict__ eb, const int* __restrict__ deg,
    float* __restrict__ hout,
    const float* __restrict__ Wq1, const float* __restrict__ bq1,
    const float* __restrict__ gq, const float* __restrict__ betaq,
    const float* __restrict__ Wq2, const float* __restrict__ bq2,
    const float* __restrict__ Wv1, const float* __restrict__ bv1,
    const float* __restrict__ gv, const float* __restrict__ betav,
    const float* __restrict__ Wv2, const float* __restrict__ bv2)
{
    __shared__ float ht[64], ut[64], xgt[64];
    __shared__ float scr[4][4][64];     // per-wave 4-edge vector scratch
    __shared__ float xgc[MAXDEG][64];   // per-edge xg cache
    __shared__ float ec[MAXDEG];        // per-edge attention logit
    __shared__ float redA[4][64], redB[4][64];
    __shared__ float sws[4];
    __shared__ float sA[2];             // a_s[t], a_d[t]
    __shared__ float sEm;

    int lane = threadIdx.x & 63;
    int wv = threadIdx.x >> 6;
    int ntgt = (LM == 2) ? 1 : min(cntp[0], tcap);

    for (int w = blockIdx.x; w < ntgt; w += gridDim.x) {
        int t = (LM == 2) ? 0 : tlist[w];
        if (wv == 0) {
            float h = node_h<LM>(t, lane, x, Wn, bn, gn, betan, hin);
            ht[lane] = h;
            float u = bc1[lane], xg = 0.f;
            #pragma unroll 4
            for (int k = 0; k < 64; k++) {
                float b = ht[k];
                u  += b * Wc1[k * 64 + lane];
                xg += b * Wg[k * 64 + lane];
            }
            ut[lane] = u; xgt[lane] = xg;
            float a_st = wsum64(xg * atts[lane]);
            float a_dt = wsum64(xg * attd[lane]);
            if (lane == 0) { sA[0] = a_st; sA[1] = a_dt; }
        }
        __syncthreads();
        int dg = deg[(LM == 2) ? 0 : w]; if (dg > MAXDEG) dg = MAXDEG;
        float a_dt = sA[1];
        float aggw = -INFINITY;

        for (int base = wv * 4; base < dg; base += 16) {
            int ne = dg - base; if (ne > 4) ne = 4;
            #pragma unroll
            for (int e = 0; e < 4; e++) {
                if (e < ne) {
                    int s = eb[w * MAXDEG + base + e];
                    scr[wv][e][lane] = node_h<LM>(s, lane, x, Wn, bn, gn, betan, hin);
                }
            }
            float v[4] = {0.f, 0.f, 0.f, 0.f};
            float g[4] = {0.f, 0.f, 0.f, 0.f};
            #pragma unroll 4
            for (int k = 0; k < 64; k++) {
                float wc = Wc1[(64 + k) * 64 + lane];
                float wg = Wg[k * 64 + lane];
                #pragma unroll
                for (int e = 0; e < 4; e++) {
                    float b = scr[wv][e][k];
                    v[e] += b * wc;
                    g[e] += b * wg;
                }
            }
            float ut_l = ut[lane];
            #pragma unroll
            for (int e = 0; e < 4; e++) scr[wv][e][lane] = fmaxf(ut_l + v[e], 0.f);
            float m[4];
            #pragma unroll
            for (int e = 0; e < 4; e++) m[e] = bc2[lane];
            #pragma unroll 4
            for (int k = 0; k < 64; k++) {
                float wc2v = Wc2[k * 64 + lane];
                #pragma unroll
                for (int e = 0; e < 4; e++) m[e] += scr[wv][e][k] * wc2v;
            }
            #pragma unroll
            for (int e = 0; e < 4; e++) {
                if (e < ne) {
                    aggw = fmaxf(aggw, m[e]);
                    int j = base + e;
                    xgc[j][lane] = g[e];
                    float a_ss = wsum64(g[e] * atts[lane]);
                    if (lane == 0) ec[j] = lrelu02(a_ss + a_dt);
                }
            }
        }
        redA[wv][lane] = aggw;
        __syncthreads();

        if (wv == 0) {
            float es = lrelu02(sA[0] + sA[1]);
            float mm = es;
            for (int j = lane; j < dg; j += 64) mm = fmaxf(mm, ec[j]);
            mm = wmax64(mm);
            if (lane == 0) sEm = mm;
        }
        __syncthreads();
        float em = sEm;
        float attv = 0.f, wsv = 0.f;
        for (int j = wv; j < dg; j += 4) {
            float wj = expf(ec[j] - em);
            attv += wj * xgc[j][lane];
            wsv += wj;
        }
        redB[wv][lane] = attv;
        if (lane == 0) sws[wv] = wsv;
        __syncthreads();

        if (wv == 0) {
            float agg = fmaxf(fmaxf(redA[0][lane], redA[1][lane]),
                              fmaxf(redA[2][lane], redA[3][lane]));
            if (dg == 0) agg = 0.f;   // PyG scatter-max: empty segment -> 0
            float es = lrelu02(sA[0] + sA[1]);
            float wself = expf(es - em);
            float att = redB[0][lane] + redB[1][lane] + redB[2][lane] + redB[3][lane]
                      + wself * xgt[lane];
            float wsum = sws[0] + sws[1] + sws[2] + sws[3] + wself;
            float hv = fmaxf(ht[lane] + agg + att / wsum + bgv[lane], 0.f);
            if (LM == 2) {
                heads_eval(hv, lane, Wq1, bq1, gq, betaq, Wq2, bq2,
                           Wv1, bv1, gv, betav, Wv2, bv2, hout);
            } else {
                hout[t * HD + lane] = hv;
            }
        }
        __syncthreads();
    }
}

extern "C" void kernel_launch(void* const* d_in, const int* in_sizes, int n_in,
                              void* d_out, int out_size, void* d_ws, size_t ws_size,
                              hipStream_t stream) {
    const float* x        = (const float*)d_in[0];
    const int*   ei       = (const int*)d_in[1];
    // d_in[2] edge_attr and d_in[7..10] (edge encoder) are dead code in the reference
    const float* Wn       = (const float*)d_in[3];
    const float* bn       = (const float*)d_in[4];
    const float* gn       = (const float*)d_in[5];
    const float* betan    = (const float*)d_in[6];
    const float* Wc1      = (const float*)d_in[11];
    const float* bc1      = (const float*)d_in[12];
    const float* Wc2      = (const float*)d_in[13];
    const float* bc2      = (const float*)d_in[14];
    const float* Wg       = (const float*)d_in[15];
    const float* att_src  = (const float*)d_in[16];
    const float* att_dst  = (const float*)d_in[17];
    const float* bg       = (const float*)d_in[18];
    const float* Wq1      = (const float*)d_in[19];
    const float* bq1      = (const float*)d_in[20];
    const float* gq       = (const float*)d_in[21];
    const float* betaq    = (const float*)d_in[22];
    const float* Wq2      = (const float*)d_in[23];
    const float* bq2      = (const float*)d_in[24];
    const float* Wv1      = (const float*)d_in[25];
    const float* bv1      = (const float*)d_in[26];
    const float* gv       = (const float*)d_in[27];
    const float* betav    = (const float*)d_in[28];
    const float* Wv2      = (const float*)d_in[29];
    const float* bv2      = (const float*)d_in[30];

    // ---- workspace layout (~31 MB)
    float* hB   = (float*)d_ws;                      // h1, N*64
    float* hA   = hB + (size_t)N_NODES * HD;         // h2, N*64
    int* need1  = (int*)(hA + (size_t)N_NODES * HD); // zero-zone start
    int* need2  = need1 + N_NODES;
    int* deg1   = need2 + N_NODES;                   // T_CAP
    int* deg2   = deg1 + T_CAP;                      // T2_CAP
    int* deg3   = deg2 + T2_CAP;                     // 4
    int* cnt    = deg3 + 4;                          // 8   (zero-zone end)
    int* idx1   = cnt + 8;                           // N
    int* idx2   = idx1 + N_NODES;                    // N
    int* list1  = idx2 + N_NODES;                    // T_CAP
    int* list2  = list1 + T_CAP;                     // T2_CAP
    int* eb1    = list2 + T2_CAP;                    // T_CAP*MAXDEG
    int* eb2    = eb1 + (size_t)T_CAP * MAXDEG;      // T2_CAP*MAXDEG
    int* eb3    = eb2 + (size_t)T2_CAP * MAXDEG;     // MAXDEG

    size_t zero_ints = (size_t)2 * N_NODES + T_CAP + T2_CAP + 12;
    hipMemsetAsync(need1, 0, zero_ints * sizeof(int), stream);

    const int EB = (N_EDGES + 255) / 256;
    const int NB = (N_NODES + 255) / 256;

    k_mark2<<<EB, 256, 0, stream>>>(ei, need1, need2);
    k_mark1<<<EB, 256, 0, stream>>>(ei, need2, need1);
    k_compact<<<NB, 256, 0, stream>>>(need1, need2, list1, list2, idx1, idx2, cnt);
    k_bucket<<<EB, 256, 0, stream>>>(ei, need1, need2, idx1, idx2,
                                     eb1, deg1, eb2, deg2, eb3, deg3);

    // layer 0: targets list1 (~290), sources encoded from x on the fly -> hB
    k_layer<0><<<512, 256, 0, stream>>>(
        x, Wn, bn, gn, betan, (const float*)nullptr,
        Wc1 + 0 * 2 * HD * HD, bc1 + 0 * HD, Wc2 + 0 * HD * HD, bc2 + 0 * HD,
        Wg + 0 * HD * HD, att_src + 0 * HD, att_dst + 0 * HD, bg + 0 * HD,
        list1, cnt + 0, T_CAP, eb1, deg1, hB,
        Wq1, bq1, gq, betaq, Wq2, bq2, Wv1, bv1, gv, betav, Wv2, bv2);

    // layer 1: targets list2 (~17), h from hB -> hA
    k_layer<1><<<64, 256, 0, stream>>>(
        x, Wn, bn, gn, betan, hB,
        Wc1 + 1 * 2 * HD * HD, bc1 + 1 * HD, Wc2 + 1 * HD * HD, bc2 + 1 * HD,
        Wg + 1 * HD * HD, att_src + 1 * HD, att_dst + 1 * HD, bg + 1 * HD,
        list2, cnt + 1, T2_CAP, eb2, deg2, hA,
        Wq1, bq1, gq, betaq, Wq2, bq2, Wv1, bv1, gv, betav, Wv2, bv2);

    // layer 2: target {0}, h from hA -> heads -> d_out
    k_layer<2><<<1, 256, 0, stream>>>(
        x, Wn, bn, gn, betan, hA,
        Wc1 + 2 * 2 * HD * HD, bc1 + 2 * HD, Wc2 + 2 * HD * HD, bc2 + 2 * HD,
        Wg + 2 * HD * HD, att_src + 2 * HD, att_dst + 2 * HD, bg + 2 * HD,
        (const int*)nullptr, cnt + 1, 1, eb3, deg3, (float*)d_out,
        Wq1, bq1, gq, betaq, Wq2, bq2, Wv1, bv1, gv, betav, Wv2, bv2);
}